// Round 12
// baseline (86.202 us; speedup 1.0000x reference)
//
#include <hip/hip_runtime.h>
#include <hip/hip_bf16.h>
#include <float.h>

// Problem constants (fixed by setup_inputs)
constexpr int B = 8, N = 4096, M = 4096, E = 12288;
constexpr int TB = 512;
constexpr int EDGE_BLOCKS = (B * E) / TB;       // 192
constexpr int SWEEP_BLOCKS = B * 16 * 2;        // 256: b x nblk(16) x mhalf(2)
// ws layout (float offsets):
constexpr size_t BFRAG = 0;                      // 8*128*64*8 shorts = 262144 floats
constexpr size_t ROWP  = 262144;                 // [b*2+mh][nt<128][row<32] = 65536
constexpr size_t COLP  = 327680;                 // [(b*2+mh)*16+nblk][2048]  = 524288
constexpr size_t EOFF  = 851968;                 // 2*192 edge partials
constexpr size_t SUMS  = 852352;                 // 64 final1 block sums
// All slots written unconditionally -> 0xAA poison harmless, no init kernel.

typedef short bf16x8  __attribute__((ext_vector_type(8)));
typedef float f32x16  __attribute__((ext_vector_type(16)));

__device__ __forceinline__ unsigned short f2bf(float x) {
    unsigned u = __float_as_uint(x);
    unsigned r = u + 0x7FFFu + ((u >> 16) & 1u);   // RNE
    return (unsigned short)(r >> 16);
}
__device__ __forceinline__ float bf2f(unsigned short h) {
    return __uint_as_float(((unsigned)h) << 16);
}
constexpr unsigned short BF_ONE = 0x3F80;

// ---- pack gt points into MFMA B-fragments (lane-ordered) ----
__global__ __launch_bounds__(256) void pack_kernel(
    const float* __restrict__ gt, unsigned short* __restrict__ bfrag) {
    const int i = blockIdx.x * 256 + threadIdx.x;   // b*4096 + tile*32 + c
    const float* p = gt + (size_t)i * 3;
    const float x = p[0], y = p[1], z = p[2];
    const unsigned short hx = f2bf(x), hy = f2bf(y), hz = f2bf(z);
    const float fx = bf2f(hx), fy = bf2f(hy), fz = bf2f(hz);
    const unsigned short lx = f2bf(x - fx), ly = f2bf(y - fy), lz = f2bf(z - fz);
    const float c = x * x + y * y + z * z;
    const unsigned short ch = f2bf(c);
    const unsigned short cl = f2bf(c - bf2f(ch));
    // -2*hi / -2*lo (exact scalings of bf16 values)
    const unsigned short ax = f2bf(-2.f * fx), bx = f2bf(-2.f * bf2f(lx));
    const unsigned short ay = f2bf(-2.f * fy), by = f2bf(-2.f * bf2f(ly));
    const unsigned short az = f2bf(-2.f * fz), bz = f2bf(-2.f * bf2f(lz));

    unsigned short* d0 = bfrag + (size_t)(((i >> 5) * 64) + (i & 31)) * 8;
    unsigned short* d1 = d0 + 32 * 8;
    // k=0..7 (lanes 0-31): x,y cross slots
    d0[0] = ax; d0[1] = ax; d0[2] = bx; d0[3] = bx;
    d0[4] = ay; d0[5] = ay; d0[6] = by; d0[7] = by;
    // k=8..15 (lanes 32-63): z cross, |p|^2 hi/lo, ones (for |q|^2 slots)
    d1[0] = az; d1[1] = az; d1[2] = bz; d1[3] = bz;
    d1[4] = ch; d1[5] = cl; d1[6] = BF_ONE; d1[7] = BF_ONE;
}

// ---- fused: edge blocks (bid<192) + MFMA chamfer sweep blocks ----
__global__ __launch_bounds__(TB) void sweep_kernel(
    const float* __restrict__ pred, const unsigned short* __restrict__ bfrag,
    const int* __restrict__ edges, float* __restrict__ wsf) {
    const int bid = blockIdx.x;
    const int t = threadIdx.x;
    __shared__ unsigned colmin[2048];
    __shared__ float wsum[8], wsum2[8];

    if (bid >= EDGE_BLOCKS) {
        const int sb   = bid - EDGE_BLOCKS;        // 0..255
        const int b    = sb >> 5;
        const int nblk = (sb & 31) >> 1;
        const int mh   = sb & 1;
        const int wv = t >> 6, l = t & 63;
        const int nt = nblk * 8 + wv;              // this wave's n-tile

        for (int i = t; i < 2048; i += TB) colmin[i] = 0xFFFFFFFFu;

        // build A-fragment in-register: lane l -> row = l&31, k = (l>>5)*8+j
        const float* qp = pred + ((size_t)b * N + nt * 32 + (l & 31)) * 3;
        const float x = qp[0], y = qp[1], z = qp[2];
        const unsigned short hx = f2bf(x), hy = f2bf(y), hz = f2bf(z);
        const unsigned short lx = f2bf(x - bf2f(hx));
        const unsigned short ly = f2bf(y - bf2f(hy));
        const unsigned short lz = f2bf(z - bf2f(hz));
        const float d = x * x + y * y + z * z;
        const unsigned short dh = f2bf(d);
        const unsigned short dl = f2bf(d - bf2f(dh));
        bf16x8 af;
        if (l < 32) {
            af[0] = (short)hx; af[1] = (short)lx; af[2] = (short)hx; af[3] = (short)lx;
            af[4] = (short)hy; af[5] = (short)ly; af[6] = (short)hy; af[7] = (short)ly;
        } else {
            af[0] = (short)hz; af[1] = (short)lz; af[2] = (short)hz; af[3] = (short)lz;
            af[4] = (short)BF_ONE; af[5] = (short)BF_ONE; af[6] = (short)dh; af[7] = (short)dl;
        }
        __syncthreads();                            // colmin init visible

        const unsigned short* bp =
            bfrag + ((size_t)((b * 128 + mh * 64) * 64) + l) * 8;
        float rowacc[16];
#pragma unroll
        for (int r = 0; r < 16; ++r) rowacc[r] = FLT_MAX;
        f32x16 zacc = {};

        bf16x8 bcur = *(const bf16x8*)bp;
        for (int mt = 0; mt < 64; ++mt) {
            const int nx = (mt + 1 < 64) ? mt + 1 : 63;
            bf16x8 bnxt = *(const bf16x8*)(bp + (size_t)nx * 512);
            f32x16 D = __builtin_amdgcn_mfma_f32_32x32x16_bf16(af, bcur, zacc, 0, 0, 0);
#pragma unroll
            for (int r = 0; r < 16; ++r) rowacc[r] = fminf(rowacc[r], D[r]);
            // column (gt-side) min of this fragment: min over 32 rows
            float t1, t2, t3, t4, t5, u1, u2;
            asm("v_min3_f32 %0, %1, %2, %3" : "=v"(t1) : "v"(D[0]),  "v"(D[1]),  "v"(D[2]));
            asm("v_min3_f32 %0, %1, %2, %3" : "=v"(t2) : "v"(D[3]),  "v"(D[4]),  "v"(D[5]));
            asm("v_min3_f32 %0, %1, %2, %3" : "=v"(t3) : "v"(D[6]),  "v"(D[7]),  "v"(D[8]));
            asm("v_min3_f32 %0, %1, %2, %3" : "=v"(t4) : "v"(D[9]),  "v"(D[10]), "v"(D[11]));
            asm("v_min3_f32 %0, %1, %2, %3" : "=v"(t5) : "v"(D[12]), "v"(D[13]), "v"(D[14]));
            asm("v_min3_f32 %0, %1, %2, %3" : "=v"(u1) : "v"(t1), "v"(t2), "v"(t3));
            asm("v_min3_f32 %0, %1, %2, %3" : "=v"(u2) : "v"(t4), "v"(t5), "v"(D[15]));
            float colv = fminf(u1, u2);
            colv = fminf(colv, __shfl_xor(colv, 32, 64));
            atomicMin(&colmin[mt * 32 + (l & 31)], __float_as_uint(fmaxf(colv, 0.f)));
            bcur = bnxt;
        }

        // finalize row mins: butterfly over the 32 columns held across lanes
#pragma unroll
        for (int r = 0; r < 16; ++r) {
            float v = rowacc[r];
            v = fminf(v, __shfl_xor(v, 1, 64));
            v = fminf(v, __shfl_xor(v, 2, 64));
            v = fminf(v, __shfl_xor(v, 4, 64));
            v = fminf(v, __shfl_xor(v, 8, 64));
            v = fminf(v, __shfl_xor(v, 16, 64));
            rowacc[r] = v;
        }
        if ((l & 31) == 0) {
            float* rp = wsf + ROWP + ((size_t)(b * 2 + mh) * 128 + nt) * 32;
            const int hb = (l >> 5) * 4;
#pragma unroll
            for (int r = 0; r < 16; ++r)
                rp[(r & 3) + 8 * (r >> 2) + hb] = fmaxf(rowacc[r], 0.f);
        }
        __syncthreads();                            // all col atomics done
        float* cp = wsf + COLP + (size_t)((b * 2 + mh) * 16 + nblk) * 2048;
        for (int i = t; i < 2048; i += TB)
            cp[i] = __uint_as_float(colmin[i]);
    } else {
        // ---------------- edge-length block ----------------
        const int eg = bid * TB + t;
        const int b  = eg / E;
        const int e  = eg - b * E;
        const int i0 = edges[2 * e], i1 = edges[2 * e + 1];
        const float* p0 = pred + ((size_t)b * N + i0) * 3;
        const float* p1 = pred + ((size_t)b * N + i1) * 3;
        const float dx = p0[0] - p1[0];
        const float dy = p0[1] - p1[1];
        const float dz = p0[2] - p1[2];
        float L  = sqrtf(dx * dx + dy * dy + dz * dz);
        float L2 = L * L;
#pragma unroll
        for (int o = 32; o > 0; o >>= 1) {
            L  += __shfl_down(L, o, 64);
            L2 += __shfl_down(L2, o, 64);
        }
        const int wv = t >> 6;
        if ((t & 63) == 0) { wsum[wv] = L; wsum2[wv] = L2; }
        __syncthreads();
        if (t == 0) {
            float a = 0.0f, c = 0.0f;
#pragma unroll
            for (int w = 0; w < 8; w++) { a += wsum[w]; c += wsum2[w]; }
            wsf[EOFF + 2 * bid]     = a;
            wsf[EOFF + 2 * bid + 1] = c;
        }
    }
}

// ---- reduce partial mins -> sqrt -> 64 block sums ----
__global__ __launch_bounds__(512) void final1_kernel(
    const float* __restrict__ wsf, float* __restrict__ sums) {
    const int g = blockIdx.x * 512 + threadIdx.x;   // 0..32767
    const int b = g >> 12, i = g & 4095;
    // gt-side (column) min over 16 nblk partials
    const int mh = i >> 11, ci = i & 2047;
    const float* cp = wsf + COLP + (size_t)((b * 2 + mh) * 16) * 2048 + ci;
    float cm = cp[0];
#pragma unroll
    for (int k = 1; k < 16; ++k) cm = fminf(cm, cp[(size_t)k * 2048]);
    // pred-side (row) min over the 2 m-halves
    const float* rp = wsf + ROWP + (size_t)b * 2 * 4096 + i;
    const float rm = fminf(rp[0], rp[4096]);
    float sv = sqrtf(cm) + sqrtf(rm);
#pragma unroll
    for (int o = 32; o > 0; o >>= 1) sv += __shfl_down(sv, o, 64);
    __shared__ float w[8];
    if ((threadIdx.x & 63) == 0) w[threadIdx.x >> 6] = sv;
    __syncthreads();
    if (threadIdx.x == 0) {
        float s = 0.f;
#pragma unroll
        for (int k = 0; k < 8; ++k) s += w[k];
        sums[blockIdx.x] = s;
    }
}

__global__ __launch_bounds__(256) void final2_kernel(
    const float* __restrict__ wsf, const float* __restrict__ sums,
    float* __restrict__ out) {
    const int t = threadIdx.x;
    float sc = (t < 64) ? sums[t] : 0.f;
    float s1 = 0.f, s2 = 0.f;
    if (t < EDGE_BLOCKS) {
        s1 = wsf[EOFF + 2 * t];
        s2 = wsf[EOFF + 2 * t + 1];
    }
#pragma unroll
    for (int o = 32; o > 0; o >>= 1) {
        sc += __shfl_down(sc, o, 64);
        s1 += __shfl_down(s1, o, 64);
        s2 += __shfl_down(s2, o, 64);
    }
    __shared__ float w[3][4];
    const int wv = t >> 6, ln = t & 63;
    if (ln == 0) { w[0][wv] = sc; w[1][wv] = s1; w[2][wv] = s2; }
    __syncthreads();
    if (t == 0) {
        float S = 0.f, A = 0.f, C = 0.f;
#pragma unroll
        for (int i = 0; i < 4; i++) { S += w[0][i]; A += w[1][i]; C += w[2][i]; }
        const float K = (float)(B * E);
        const float var = (C - A * A / K) / (K - 1.0f);
        out[0] = S / 32768.0f + 0.1f * var;
    }
}

extern "C" void kernel_launch(void* const* d_in, const int* in_sizes, int n_in,
                              void* d_out, int out_size, void* d_ws, size_t ws_size,
                              hipStream_t stream) {
    const float* pred  = (const float*)d_in[0];
    const float* gt    = (const float*)d_in[1];
    const int*   edges = (const int*)d_in[2];
    float* out = (float*)d_out;
    float* wsf = (float*)d_ws;
    unsigned short* bfrag = (unsigned short*)d_ws;   // BFRAG at offset 0
    float* sums = wsf + SUMS;

    pack_kernel<<<(B * M) / 256, 256, 0, stream>>>(gt, bfrag);
    sweep_kernel<<<EDGE_BLOCKS + SWEEP_BLOCKS, TB, 0, stream>>>(pred, bfrag, edges, wsf);
    final1_kernel<<<64, 512, 0, stream>>>(wsf, sums);
    final2_kernel<<<1, 256, 0, stream>>>(wsf, sums, out);
}